// Round 2
// baseline (284.816 us; speedup 1.0000x reference)
//
#include <hip/hip_runtime.h>
#include <hip/hip_bf16.h>
#include <math.h>

// Problem constants
#define Bn   32
#define Cn   684
#define Hn   16
#define Wn   64
#define HWn  1024
#define HIDn 256
#define An   512
#define KKn  121           // 11*11
#define CREAL 805          // 684 + 121
#define CPAD 832           // 26 chunks of 32
#define NSTEP 26
#define NBLK 256           // a-columns per energy block (N-split x2)

// Output layout (flat fp32): context [32,684] | alpha [32,1024] | alpha_sum_new [32,1024]
#define OUT_ALPHA 21888
#define OUT_ASUM  (21888 + 32768)

typedef short short8 __attribute__((ext_vector_type(8)));     // 8 bf16 = 4 VGPRs
typedef float floatx4 __attribute__((ext_vector_type(4)));    // MFMA acc

__device__ __forceinline__ unsigned short f2bf(float f) {
    union { float f; unsigned int i; } v; v.f = f;
    unsigned int i = v.i;
    return (unsigned short)((i + 0x7fffu + ((i >> 16) & 1u)) >> 16);
}
// f32 pair -> packed bf16 (RTNE), lowers to v_cvt_pk_bf16_f32 on gfx950
__device__ __forceinline__ unsigned int cvt2(float lo, float hi) {
    __hip_bfloat162 h = __float22bfloat162_rn(float2{lo, hi});
    union { __hip_bfloat162 h; unsigned int u; } cv; cv.h = h;
    return cv.u;
}

// Bfr fragment-order index: element (n, k) -> short index.
// Wave-frag read: 16B at ((n>>4)*26 + k>>5)*64 + ((k>>3)&3)*16 + (n&15), j = k&7.
__device__ __forceinline__ size_t bfr_idx(int n, int k) {
    return ((((size_t)(n >> 4) * 26 + (k >> 5)) * 64
             + ((k >> 3) & 3) * 16 + (n & 15)) * 8) + (k & 7);
}

// ---------------------------------------------------------------------------
// K_prep: blocks 0..511 build Bfr row a (fragment-ordered); 512..543: query b.
__global__ __launch_bounds__(256) void k_prep(
    const float* __restrict__ hidden,
    const float* __restrict__ Wh,
    const float* __restrict__ bh,
    const float* __restrict__ bec,
    const float* __restrict__ Wec,
    const float* __restrict__ Wac,
    const float* __restrict__ Waw,
    float* __restrict__ query,
    unsigned short* __restrict__ Bfr)
{
    __shared__ float sbuf[512];
    const int blk = blockIdx.x, t = threadIdx.x;
    if (blk < 512) {
        const int a = blk;
        sbuf[t]       = Waw[(size_t)a * 512 + t];
        sbuf[t + 256] = Waw[(size_t)a * 512 + t + 256];
        __syncthreads();
        for (int cp = t; cp < Cn; cp += 256)
            Bfr[bfr_idx(a, cp)] = f2bf(Wec[(size_t)a * Cn + cp]);
        if (t < KKn) {
            float s = 0.f;
            #pragma unroll 8
            for (int k = 0; k < 512; ++k)
                s = fmaf(sbuf[k], Wac[k * KKn + t], s);
            Bfr[bfr_idx(a, Cn + t)] = f2bf(s);
        }
        for (int cp = CREAL + t; cp < CPAD; cp += 256)
            Bfr[bfr_idx(a, cp)] = 0;
    } else {
        const int b = blk - 512;
        sbuf[t] = (t < HIDn) ? hidden[b * HIDn + t] : 0.f;
        __syncthreads();
        for (int a = t; a < An; a += 256) {
            const float4* wp = (const float4*)(Wh + (size_t)a * HIDn);
            float s = bh[a] + bec[a];
            #pragma unroll 8
            for (int i = 0; i < HIDn / 4; ++i) {
                float4 w = wp[i];
                s = fmaf(sbuf[4 * i],     w.x, s);
                s = fmaf(sbuf[4 * i + 1], w.y, s);
                s = fmaf(sbuf[4 * i + 2], w.z, s);
                s = fmaf(sbuf[4 * i + 3], w.w, s);
            }
            query[b * An + a] = s;
        }
    }
}

// ---------------------------------------------------------------------------
// K_energy v6: BARRIER-FREE K-loop.
//  - B fragments: direct global->reg dwordx4 from fragment-ordered Bfr
//    (L2-resident 852KB), 1KB coalesced per wave-load. No B LDS, no DMA.
//  - A: per-wave private LDS ping-pong (wave stages its own 64m x 32k chunk:
//    coalesced float4 X loads -> cvt_pk bf16 -> 4 ds_write_b128). Same-wave
//    in-order DS => no __syncthreads in the loop (2 barriers total).
//  - LDS row stride 80B: write banks 16(mg&1)+4kg and read banks 20r+4q both
//    cover all 32 banks per 8-lane group => conflict-free, no swizzle.
//  - unroll-2 ping-pong with NAMED reg sets (no runtime-indexed private
//    arrays -> no scratch), 1-chunk-ahead A/B prefetch.
// Grid: 1D 1024, XCD-pair swizzle: xcd = d&7, nh = (d>>3)&1 so the two
// nh-halves sharing an X-slice land on the same XCD's L2.
__global__ __launch_bounds__(256, 3) void k_energy(
    const float* __restrict__ X,
    const float* __restrict__ asum,
    const float* __restrict__ Wv,
    const float* __restrict__ query,
    const unsigned short* __restrict__ Bfr,
    float* __restrict__ energy)
{
    __shared__ __align__(16) unsigned int As[4][2][64 * 20];  // 40,960B
    __shared__ float plane[11 * 74 + 2];
    __shared__ float qs[NBLK];
    __shared__ float wvs[NBLK];

    const int t = threadIdx.x;
    const int d = blockIdx.x;
    const int nh  = (d >> 3) & 1;
    const int pid = (d >> 4) * 8 + (d & 7);
    const int hh = pid & 15, b = pid >> 4;
    const int w = t >> 6, lane = t & 63;
    const int q = lane >> 4, r = lane & 15;
    const int nbase = nh * NBLK;
    const int mg = lane & 15, kg = lane >> 4;   // A staging: 4m x 8k per lane

    const float* Xb = X + (size_t)b * Cn * HWn + hh * Wn;
    const unsigned short* Bp = Bfr + (size_t)(nh * 16 + w * 4) * 26 * 512;

    // ---- prologue: plane / qs / wvs, ONE barrier
    for (int i = t; i < 11 * 74; i += 256) {
        int di = i / 74, cc = i - di * 74;
        int h2 = hh + di - 5, w2 = cc - 5;
        float v = 0.f;
        if (h2 >= 0 && h2 < Hn && w2 >= 0 && w2 < Wn)
            v = asum[b * HWn + h2 * Wn + w2];
        plane[i] = v;
    }
    qs[t]  = query[b * An + nbase + t];
    wvs[t] = Wv[nbase + t];
    __syncthreads();

    unsigned int* A0 = &As[w][0][0];
    unsigned int* A1 = &As[w][1][0];

    __align__(16) float va[32];      // 8 k-rows x 4 m, fully unrolled -> VGPRs
    short8 b0[4], b1[4], af[4];

#define LOADX(CH) {                                                           \
    const int c0 = (CH) * 32 + kg * 8;                                        \
    if (c0 + 7 < Cn) {                                                        \
        const float* xp = Xb + (size_t)c0 * HWn + mg * 4;                     \
        _Pragma("unroll")                                                     \
        for (int j = 0; j < 8; ++j)                                           \
            *(float4*)&va[j * 4] = *(const float4*)(xp + (size_t)j * HWn);    \
    } else {                                                                  \
        _Pragma("unroll")                                                     \
        for (int j = 0; j < 8; ++j) {                                         \
            const int row = c0 + j;                                           \
            _Pragma("unroll")                                                 \
            for (int mm = 0; mm < 4; ++mm) {                                  \
                float vv = 0.f;                                               \
                if (row < Cn) vv = Xb[(size_t)row * HWn + mg * 4 + mm];       \
                else if (row < CREAL) {                                       \
                    int ij = row - Cn; int di = ij / 11, dj = ij - di * 11;   \
                    vv = plane[di * 74 + mg * 4 + mm + dj];                   \
                }                                                             \
                va[j * 4 + mm] = vv;                                          \
            }                                                                 \
        }                                                                     \
    } }

#define CVTWR(DST) {                                                          \
    _Pragma("unroll")                                                         \
    for (int mi = 0; mi < 4; ++mi) {                                          \
        uint4 u;                                                              \
        u.x = cvt2(va[0 * 4 + mi], va[1 * 4 + mi]);                           \
        u.y = cvt2(va[2 * 4 + mi], va[3 * 4 + mi]);                           \
        u.z = cvt2(va[4 * 4 + mi], va[5 * 4 + mi]);                           \
        u.w = cvt2(va[6 * 4 + mi], va[7 * 4 + mi]);                           \
        *(uint4*)&(DST)[(mg * 4 + mi) * 20 + kg * 4] = u;                     \
    } }

#define LOADB(DSTB, CH) {                                                     \
    _Pragma("unroll")                                                         \
    for (int nf = 0; nf < 4; ++nf)                                            \
        DSTB[nf] = *(const short8*)(Bp + ((size_t)nf * 26 + (CH)) * 512       \
                                       + lane * 8);                           \
    }

#define READA(SRC) {                                                          \
    _Pragma("unroll")                                                         \
    for (int mf = 0; mf < 4; ++mf)                                            \
        af[mf] = *(const short8*)&(SRC)[(mf * 16 + r) * 20 + q * 4];          \
    }

#define MFMA16(BF) {                                                          \
    _Pragma("unroll")                                                         \
    for (int mf = 0; mf < 4; ++mf)                                            \
        _Pragma("unroll")                                                     \
        for (int nf = 0; nf < 4; ++nf)                                        \
            acc[mf][nf] = __builtin_amdgcn_mfma_f32_16x16x32_bf16(            \
                af[mf], BF[nf], acc[mf][nf], 0, 0, 0);                        \
    }

    floatx4 acc[4][4];
    #pragma unroll
    for (int mf = 0; mf < 4; ++mf)
        #pragma unroll
        for (int nf = 0; nf < 4; ++nf)
            acc[mf][nf] = (floatx4){0.f, 0.f, 0.f, 0.f};

    // stage chunk 0
    LOADX(0); CVTWR(A0);
    LOADB(b0, 0);

    for (int ch = 0; ch < NSTEP; ch += 2) {
        // even chunk ch: frags from A0 / b0; prefetch ch+1
        LOADX(ch + 1);            // global loads issued, consumed after MFMA
        LOADB(b1, ch + 1);
        READA(A0);
        MFMA16(b0);
        CVTWR(A1);                // vmcnt wait lands here, behind the MFMAs
        // odd chunk ch+1: frags from A1 / b1; prefetch ch+2
        if (ch + 2 < NSTEP) { LOADX(ch + 2); LOADB(b0, ch + 2); }
        READA(A1);
        MFMA16(b1);
        if (ch + 2 < NSTEP) CVTWR(A0);
    }

#undef LOADX
#undef CVTWR
#undef LOADB
#undef READA
#undef MFMA16

    // ---- epilogue: e[m] = sum_n Wv[n]*tanh(acc + query[n]); partial over 256 a
    float ep[16];
    #pragma unroll
    for (int i = 0; i < 16; ++i) ep[i] = 0.f;
    #pragma unroll
    for (int nf = 0; nf < 4; ++nf) {
        int nl = w * 64 + nf * 16 + r;
        float qv = qs[nl], wv = wvs[nl];
        #pragma unroll
        for (int mf = 0; mf < 4; ++mf)
            #pragma unroll
            for (int rg = 0; rg < 4; ++rg) {
                float x = acc[mf][nf][rg] + qv;
                float e2 = __expf(2.f * x);
                float th = 1.f - 2.f * __builtin_amdgcn_rcpf(e2 + 1.f);
                ep[mf * 4 + rg] += wv * th;
            }
    }
    __syncthreads();               // all waves done with As before overlay
    float* red = (float*)As;       // 64 x 65 floats (16,640B <= 40,960B)
    #pragma unroll
    for (int mf = 0; mf < 4; ++mf)
        #pragma unroll
        for (int rg = 0; rg < 4; ++rg)
            red[(mf * 16 + q * 4 + rg) * 65 + w * 16 + r] = ep[mf * 4 + rg];
    __syncthreads();
    if (t < 64) {
        float s = 0.f;
        #pragma unroll 16
        for (int i = 0; i < 64; ++i) s += red[t * 65 + i];
        atomicAdd(&energy[b * HWn + hh * Wn + t], s);
    }
}

// ---------------------------------------------------------------------------
// K_softmax: one block per batch. alpha from energy once, written in-place
// over energy, plus alpha / alpha_sum_new outputs.
__global__ __launch_bounds__(256) void k_softmax(
    const float* __restrict__ mask,
    const float* __restrict__ asum,
    float* __restrict__ energy,     // in: energy, out: alpha
    float* __restrict__ out)
{
    __shared__ float rsm[8];
    const int b = blockIdx.x;
    const int t = threadIdx.x, lane = t & 63, wid = t >> 6;

    float e[4], ex[4];
    #pragma unroll
    for (int i = 0; i < 4; ++i) e[i] = energy[b * HWn + i * 256 + t];
    float m = fmaxf(fmaxf(e[0], e[1]), fmaxf(e[2], e[3]));
    for (int off = 32; off >= 1; off >>= 1) m = fmaxf(m, __shfl_down(m, off, 64));
    if (lane == 0) rsm[wid] = m;
    __syncthreads();
    if (t == 0)
        rsm[4] = fmaxf(fmaxf(rsm[0], rsm[1]), fmaxf(rsm[2], rsm[3]));
    __syncthreads();
    const float M = rsm[4];
    float s = 0.f;
    #pragma unroll
    for (int i = 0; i < 4; ++i) {
        ex[i] = expf(e[i] - M) * mask[b * HWn + i * 256 + t];
        s += ex[i];
    }
    for (int off = 32; off >= 1; off >>= 1) s += __shfl_down(s, off, 64);
    __syncthreads();
    if (lane == 0) rsm[wid] = s;
    __syncthreads();
    if (t == 0) rsm[5] = rsm[0] + rsm[1] + rsm[2] + rsm[3] + 1e-10f;
    __syncthreads();
    const float denom = rsm[5];
    #pragma unroll
    for (int i = 0; i < 4; ++i) {
        int p = i * 256 + t;
        float a = ex[i] / denom;
        energy[b * HWn + p] = a;
        out[OUT_ALPHA + b * HWn + p] = a;
        out[OUT_ASUM  + b * HWn + p] = a + asum[b * HWn + p];
    }
}

// ---------------------------------------------------------------------------
// K_ctx: pure context GEMV. Grid (171, 32); block caches alpha in LDS,
// wave wid handles channel bx*4+wid. Streams X once.
__global__ __launch_bounds__(256) void k_ctx(
    const float* __restrict__ X,
    const float* __restrict__ alpha,
    float* __restrict__ out)
{
    __shared__ float al[1024];
    const int bx = blockIdx.x, b = blockIdx.y;
    const int t = threadIdx.x, lane = t & 63, wid = t >> 6;

    #pragma unroll
    for (int i = 0; i < 4; ++i) al[i * 256 + t] = alpha[b * HWn + i * 256 + t];
    __syncthreads();

    const int c = bx * 4 + wid;
    const float* xp = X + ((size_t)(b * Cn + c)) * HWn;
    float s2 = 0.f;
    #pragma unroll
    for (int i = 0; i < 4; ++i) {
        int off = i * 256 + lane * 4;
        float4 x = *(const float4*)(xp + off);
        float4 a = *(const float4*)(al + off);
        s2 = fmaf(a.x, x.x, s2);
        s2 = fmaf(a.y, x.y, s2);
        s2 = fmaf(a.z, x.z, s2);
        s2 = fmaf(a.w, x.w, s2);
    }
    for (int off = 32; off >= 1; off >>= 1) s2 += __shfl_down(s2, off, 64);
    if (lane == 0) out[b * Cn + c] = s2;
}

// ---------------------------------------------------------------------------
extern "C" void kernel_launch(void* const* d_in, const int* in_sizes, int n_in,
                              void* d_out, int out_size, void* d_ws, size_t ws_size,
                              hipStream_t stream)
{
    const float* X      = (const float*)d_in[0];
    const float* hidden = (const float*)d_in[1];
    const float* asum   = (const float*)d_in[2];
    const float* mask   = (const float*)d_in[3];
    const float* Wh     = (const float*)d_in[4];
    const float* bh     = (const float*)d_in[5];
    const float* Wec    = (const float*)d_in[6];
    const float* bec    = (const float*)d_in[7];
    const float* Wac    = (const float*)d_in[8];
    const float* Waw    = (const float*)d_in[9];
    const float* Wv     = (const float*)d_in[10];
    (void)in_sizes; (void)n_in; (void)out_size; (void)ws_size;

    float* out = (float*)d_out;
    float* ws = (float*)d_ws;
    float* query  = ws;                                    // 16384 floats
    float* energy = ws + 16384;                            // 32768 (energy -> alpha)
    unsigned short* Bfr = (unsigned short*)(ws + 16384 + 32768); // 512*832 bf16

    hipMemsetAsync(energy, 0, HWn * Bn * sizeof(float), stream);
    k_prep    <<<dim3(544),      dim3(256), 0, stream>>>(hidden, Wh, bh, bec,
                                                         Wec, Wac, Waw, query, Bfr);
    k_energy  <<<dim3(1024),     dim3(256), 0, stream>>>(X, asum, Wv, query, Bfr, energy);
    k_softmax <<<dim3(32),       dim3(256), 0, stream>>>(mask, asum, energy, out);
    k_ctx     <<<dim3(171, 32),  dim3(256), 0, stream>>>(X, energy, out);
}

// Round 3
// 262.245 us; speedup vs baseline: 1.0861x; 1.0861x over previous
//
#include <hip/hip_runtime.h>
#include <hip/hip_bf16.h>
#include <math.h>

// Problem constants
#define Bn   32
#define Cn   684
#define Hn   16
#define Wn   64
#define HWn  1024
#define HIDn 256
#define An   512
#define KKn  121           // 11*11
#define CREAL 805          // 684 + 121
#define CPAD 832           // 26 chunks of 32
#define NSTEP 26
#define NBLK 256           // a-columns per energy block (N-split x2)

// Output layout (flat fp32): context [32,684] | alpha [32,1024] | alpha_sum_new [32,1024]
#define OUT_ALPHA 21888
#define OUT_ASUM  (21888 + 32768)

typedef short short8 __attribute__((ext_vector_type(8)));     // 8 bf16 = 4 VGPRs
typedef float floatx4 __attribute__((ext_vector_type(4)));    // MFMA acc

__device__ __forceinline__ unsigned short f2bf(float f) {
    union { float f; unsigned int i; } v; v.f = f;
    unsigned int i = v.i;
    return (unsigned short)((i + 0x7fffu + ((i >> 16) & 1u)) >> 16);
}
// f32 pair -> packed bf16 (RTNE), lowers to v_cvt_pk_bf16_f32 on gfx950
__device__ __forceinline__ unsigned int cvt2(float lo, float hi) {
    __hip_bfloat162 h = __float22bfloat162_rn(float2{lo, hi});
    union { __hip_bfloat162 h; unsigned int u; } cv; cv.h = h;
    return cv.u;
}

// Bfr fragment-order index: element (n, k) -> short index.
// Wave reads 16B at block ((n>>4)*26 + (k>>5)), lane offset ((k>>3)&3)*16 + (n&15).
__device__ __forceinline__ size_t bfr_idx(int n, int k) {
    return ((((size_t)(n >> 4) * 26 + (k >> 5)) * 64
             + ((k >> 3) & 3) * 16 + (n & 15)) * 8) + (k & 7);
}

// ---------------------------------------------------------------------------
// K_prep: blocks 0..511 build Bfr row a (fragment-ordered); 512..543: query b.
__global__ __launch_bounds__(256) void k_prep(
    const float* __restrict__ hidden,
    const float* __restrict__ Wh,
    const float* __restrict__ bh,
    const float* __restrict__ bec,
    const float* __restrict__ Wec,
    const float* __restrict__ Wac,
    const float* __restrict__ Waw,
    float* __restrict__ query,
    unsigned short* __restrict__ Bfr)
{
    __shared__ float sbuf[512];
    const int blk = blockIdx.x, t = threadIdx.x;
    if (blk < 512) {
        const int a = blk;
        sbuf[t]       = Waw[(size_t)a * 512 + t];
        sbuf[t + 256] = Waw[(size_t)a * 512 + t + 256];
        __syncthreads();
        for (int cp = t; cp < Cn; cp += 256)
            Bfr[bfr_idx(a, cp)] = f2bf(Wec[(size_t)a * Cn + cp]);
        if (t < KKn) {
            float s = 0.f;
            #pragma unroll 8
            for (int k = 0; k < 512; ++k)
                s = fmaf(sbuf[k], Wac[k * KKn + t], s);
            Bfr[bfr_idx(a, Cn + t)] = f2bf(s);
        }
        for (int cp = CREAL + t; cp < CPAD; cp += 256)
            Bfr[bfr_idx(a, cp)] = 0;
    } else {
        const int b = blk - 512;
        sbuf[t] = (t < HIDn) ? hidden[b * HIDn + t] : 0.f;
        __syncthreads();
        for (int a = t; a < An; a += 256) {
            const float4* wp = (const float4*)(Wh + (size_t)a * HIDn);
            float s = bh[a] + bec[a];
            #pragma unroll 8
            for (int i = 0; i < HIDn / 4; ++i) {
                float4 w = wp[i];
                s = fmaf(sbuf[4 * i],     w.x, s);
                s = fmaf(sbuf[4 * i + 1], w.y, s);
                s = fmaf(sbuf[4 * i + 2], w.z, s);
                s = fmaf(sbuf[4 * i + 3], w.w, s);
            }
            query[b * An + a] = s;
        }
    }
}

// ---------------------------------------------------------------------------
// K_energy v7: round-0 structure, minimal surgical changes.
//  - B fragments: direct global->reg dwordx4 from fragment-ordered Bfr
//    (L2-resident 852KB). No B LDS, no DMA, no B bank conflicts.
//  - A: SHARED block-wide staging (256 thr stage one 64x32 chunk once),
//    double-buffered As (10,240B), one barrier per chunk, stage-before-MFMA
//    order (round-0's proven schedule; round-1 showed reorder hurts).
//  - LDS 16.6KB + __launch_bounds__(256,4): <=128 unified regs -> 4 waves/
//    SIMD, 4 blocks/CU, all 1024 blocks resident in ONE dispatch round
//    (round-0 ran 2 waves/SIMD + 2 rounds: the latency-bound signature).
//  - Epilogue: shfl_xor reduce over r-lanes + tiny red[4][64].
// Grid 1D 1024, XCD-pair swizzle (kept from R2: FETCH 91->50MB).
__device__ __forceinline__ float fetchU(const float* __restrict__ X,
                                        const float* plane,
                                        int m, int row) {
    if (row < Cn)   return X[(size_t)row * HWn + m];
    if (row < CREAL) {
        int ij = row - Cn; int di = ij / 11, dj = ij - di * 11;
        return plane[di * 74 + m + dj];
    }
    return 0.f;
}

__global__ __launch_bounds__(256, 4) void k_energy(
    const float* __restrict__ X,
    const float* __restrict__ asum,
    const float* __restrict__ Wv,
    const float* __restrict__ query,
    const unsigned short* __restrict__ Bfr,
    float* __restrict__ energy)
{
    __shared__ __align__(16) unsigned short As[2][64 * 40];   // 10,240B, stride 40
    __shared__ float plane[11 * 74 + 2];
    __shared__ float qs[NBLK];
    __shared__ float wvs[NBLK];
    __shared__ float red[4][64];

    const int t = threadIdx.x;
    const int d = blockIdx.x;
    const int nh  = (d >> 3) & 1;
    const int pid = (d >> 4) * 8 + (d & 7);
    const int hh = pid & 15, b = pid >> 4;
    const int w = t >> 6, lane = t & 63;
    const int q = lane >> 4, r = lane & 15;
    const int nbase = nh * NBLK;
    const int mA = t & 63;                 // A-staging: m index
    const int koA = t >> 6;                // A-staging: k-octet (0..3)

    const float* Xb = X + (size_t)b * Cn * HWn + hh * Wn;
    const unsigned short* Bp = Bfr + (size_t)(nh * 16 + w * 4) * 26 * 512;

    // ---- prologue: plane / qs / wvs / chunk 0
    for (int i = t; i < 11 * 74; i += 256) {
        int di = i / 74, cc = i - di * 74;
        int h2 = hh + di - 5, w2 = cc - 5;
        float v = 0.f;
        if (h2 >= 0 && h2 < Hn && w2 >= 0 && w2 < Wn)
            v = asum[b * HWn + h2 * Wn + w2];
        plane[i] = v;
    }
    qs[t]  = query[b * An + nbase + t];
    wvs[t] = Wv[nbase + t];
    // stage A chunk 0 (rows 0..31, pure X)
    {
        const float* xp = Xb + (size_t)(koA * 8) * HWn + mA;
        uint4 u;
        u.x = cvt2(xp[0],              xp[(size_t)1 * HWn]);
        u.y = cvt2(xp[(size_t)2 * HWn], xp[(size_t)3 * HWn]);
        u.z = cvt2(xp[(size_t)4 * HWn], xp[(size_t)5 * HWn]);
        u.w = cvt2(xp[(size_t)6 * HWn], xp[(size_t)7 * HWn]);
        *(uint4*)&As[0][mA * 40 + koA * 8] = u;
    }
    __syncthreads();

    floatx4 acc[4][4];
    #pragma unroll
    for (int mf = 0; mf < 4; ++mf)
        #pragma unroll
        for (int nf = 0; nf < 4; ++nf)
            acc[mf][nf] = (floatx4){0.f, 0.f, 0.f, 0.f};

    for (int ch = 0; ch < NSTEP; ++ch) {
        const int cur = ch & 1;

        // (1) B fragments for this chunk: coalesced 1KB/wave from L2
        short8 bf[4];
        #pragma unroll
        for (int nf = 0; nf < 4; ++nf)
            bf[nf] = *(const short8*)(Bp + ((size_t)(nf * 26 + ch)) * 512 + lane * 8);

        // (2) A fragments of current chunk from LDS
        short8 af[4];
        #pragma unroll
        for (int mf = 0; mf < 4; ++mf)
            af[mf] = *(const short8*)&As[cur][(mf * 16 + r) * 40 + q * 8];

        // (3) stage next chunk into other buffer (load -> cvt_pk -> ds_write;
        //     the vmcnt(0) before the pack also retires the older bf loads)
        if (ch < NSTEP - 1) {
            const int c0 = (ch + 1) * 32 + koA * 8;
            float va[8];
            if (c0 + 7 < Cn) {          // pure-X fast path
                const float* xp = Xb + (size_t)c0 * HWn + mA;
                #pragma unroll
                for (int j = 0; j < 8; ++j)
                    va[j] = xp[(size_t)j * HWn];
            } else {                     // mixed X / im2col / zero
                #pragma unroll
                for (int j = 0; j < 8; ++j)
                    va[j] = fetchU(Xb, plane, mA, c0 + j);
            }
            uint4 u;
            u.x = cvt2(va[0], va[1]);
            u.y = cvt2(va[2], va[3]);
            u.z = cvt2(va[4], va[5]);
            u.w = cvt2(va[6], va[7]);
            *(uint4*)&As[cur ^ 1][mA * 40 + koA * 8] = u;
        }

        // (4) MFMA
        #pragma unroll
        for (int mf = 0; mf < 4; ++mf)
            #pragma unroll
            for (int nf = 0; nf < 4; ++nf)
                acc[mf][nf] = __builtin_amdgcn_mfma_f32_16x16x32_bf16(
                    af[mf], bf[nf], acc[mf][nf], 0, 0, 0);

        // (5) single barrier protects the A double-buffer
        __syncthreads();
    }

    // ---- epilogue: e[m] = sum_n Wv[n]*tanh(acc + query[n])
    float ep[16];
    #pragma unroll
    for (int i = 0; i < 16; ++i) ep[i] = 0.f;
    #pragma unroll
    for (int nf = 0; nf < 4; ++nf) {
        int nl = w * 64 + nf * 16 + r;
        float qv = qs[nl], wv = wvs[nl];
        #pragma unroll
        for (int mf = 0; mf < 4; ++mf)
            #pragma unroll
            for (int rg = 0; rg < 4; ++rg) {
                float x = acc[mf][nf][rg] + qv;
                float e2 = __expf(2.f * x);
                float th = 1.f - 2.f * __builtin_amdgcn_rcpf(e2 + 1.f);
                ep[mf * 4 + rg] += wv * th;
            }
    }
    // reduce over the 16 r-lanes (lane bits 0..3) via shfl_xor
    #pragma unroll
    for (int i = 0; i < 16; ++i) {
        #pragma unroll
        for (int msk = 1; msk <= 8; msk <<= 1)
            ep[i] += __shfl_xor(ep[i], msk, 64);
    }
    if (r == 0) {
        #pragma unroll
        for (int mf = 0; mf < 4; ++mf)
            #pragma unroll
            for (int rg = 0; rg < 4; ++rg)
                red[w][mf * 16 + q * 4 + rg] = ep[mf * 4 + rg];
    }
    __syncthreads();
    if (t < 64) {
        float s = red[0][t] + red[1][t] + red[2][t] + red[3][t];
        atomicAdd(&energy[b * HWn + hh * Wn + t], s);
    }
}

// ---------------------------------------------------------------------------
// K_softmax: one block per batch. alpha from energy once, written in-place
// over energy, plus alpha / alpha_sum_new outputs.
__global__ __launch_bounds__(256) void k_softmax(
    const float* __restrict__ mask,
    const float* __restrict__ asum,
    float* __restrict__ energy,     // in: energy, out: alpha
    float* __restrict__ out)
{
    __shared__ float rsm[8];
    const int b = blockIdx.x;
    const int t = threadIdx.x, lane = t & 63, wid = t >> 6;

    float e[4], ex[4];
    #pragma unroll
    for (int i = 0; i < 4; ++i) e[i] = energy[b * HWn + i * 256 + t];
    float m = fmaxf(fmaxf(e[0], e[1]), fmaxf(e[2], e[3]));
    for (int off = 32; off >= 1; off >>= 1) m = fmaxf(m, __shfl_down(m, off, 64));
    if (lane == 0) rsm[wid] = m;
    __syncthreads();
    if (t == 0)
        rsm[4] = fmaxf(fmaxf(rsm[0], rsm[1]), fmaxf(rsm[2], rsm[3]));
    __syncthreads();
    const float M = rsm[4];
    float s = 0.f;
    #pragma unroll
    for (int i = 0; i < 4; ++i) {
        ex[i] = expf(e[i] - M) * mask[b * HWn + i * 256 + t];
        s += ex[i];
    }
    for (int off = 32; off >= 1; off >>= 1) s += __shfl_down(s, off, 64);
    __syncthreads();
    if (lane == 0) rsm[wid] = s;
    __syncthreads();
    if (t == 0) rsm[5] = rsm[0] + rsm[1] + rsm[2] + rsm[3] + 1e-10f;
    __syncthreads();
    const float denom = rsm[5];
    #pragma unroll
    for (int i = 0; i < 4; ++i) {
        int p = i * 256 + t;
        float a = ex[i] / denom;
        energy[b * HWn + p] = a;
        out[OUT_ALPHA + b * HWn + p] = a;
        out[OUT_ASUM  + b * HWn + p] = a + asum[b * HWn + p];
    }
}

// ---------------------------------------------------------------------------
// K_ctx: pure context GEMV. Grid (171, 32); block caches alpha in LDS,
// wave wid handles channel bx*4+wid. Streams X once.
__global__ __launch_bounds__(256) void k_ctx(
    const float* __restrict__ X,
    const float* __restrict__ alpha,
    float* __restrict__ out)
{
    __shared__ float al[1024];
    const int bx = blockIdx.x, b = blockIdx.y;
    const int t = threadIdx.x, lane = t & 63, wid = t >> 6;

    #pragma unroll
    for (int i = 0; i < 4; ++i) al[i * 256 + t] = alpha[b * HWn + i * 256 + t];
    __syncthreads();

    const int c = bx * 4 + wid;
    const float* xp = X + ((size_t)(b * Cn + c)) * HWn;
    float s2 = 0.f;
    #pragma unroll
    for (int i = 0; i < 4; ++i) {
        int off = i * 256 + lane * 4;
        float4 x = *(const float4*)(xp + off);
        float4 a = *(const float4*)(al + off);
        s2 = fmaf(a.x, x.x, s2);
        s2 = fmaf(a.y, x.y, s2);
        s2 = fmaf(a.z, x.z, s2);
        s2 = fmaf(a.w, x.w, s2);
    }
    for (int off = 32; off >= 1; off >>= 1) s2 += __shfl_down(s2, off, 64);
    if (lane == 0) out[b * Cn + c] = s2;
}

// ---------------------------------------------------------------------------
extern "C" void kernel_launch(void* const* d_in, const int* in_sizes, int n_in,
                              void* d_out, int out_size, void* d_ws, size_t ws_size,
                              hipStream_t stream)
{
    const float* X      = (const float*)d_in[0];
    const float* hidden = (const float*)d_in[1];
    const float* asum   = (const float*)d_in[2];
    const float* mask   = (const float*)d_in[3];
    const float* Wh     = (const float*)d_in[4];
    const float* bh     = (const float*)d_in[5];
    const float* Wec    = (const float*)d_in[6];
    const float* bec    = (const float*)d_in[7];
    const float* Wac    = (const float*)d_in[8];
    const float* Waw    = (const float*)d_in[9];
    const float* Wv     = (const float*)d_in[10];
    (void)in_sizes; (void)n_in; (void)out_size; (void)ws_size;

    float* out = (float*)d_out;
    float* ws = (float*)d_ws;
    float* query  = ws;                                    // 16384 floats
    float* energy = ws + 16384;                            // 32768 (energy -> alpha)
    unsigned short* Bfr = (unsigned short*)(ws + 16384 + 32768); // 512*832 bf16

    hipMemsetAsync(energy, 0, HWn * Bn * sizeof(float), stream);
    k_prep    <<<dim3(544),      dim3(256), 0, stream>>>(hidden, Wh, bh, bec,
                                                         Wec, Wac, Waw, query, Bfr);
    k_energy  <<<dim3(1024),     dim3(256), 0, stream>>>(X, asum, Wv, query, Bfr, energy);
    k_softmax <<<dim3(32),       dim3(256), 0, stream>>>(mask, asum, energy, out);
    k_ctx     <<<dim3(171, 32),  dim3(256), 0, stream>>>(X, energy, out);
}

// Round 4
// 238.289 us; speedup vs baseline: 1.1953x; 1.1005x over previous
//
#include <hip/hip_runtime.h>
#include <hip/hip_bf16.h>
#include <math.h>

// Problem constants
#define Bn   32
#define Cn   684
#define Hn   16
#define Wn   64
#define HWn  1024
#define HIDn 256
#define An   512
#define KKn  121           // 11*11
#define CREAL 805          // 684 + 121
#define CPAD 832           // 26 chunks of 32
#define NSTEP 26
#define NBLK 256           // a-columns per energy block (N-split x2)

// Output layout (flat fp32): context [32,684] | alpha [32,1024] | alpha_sum_new [32,1024]
#define OUT_ALPHA 21888
#define OUT_ASUM  (21888 + 32768)

typedef short short8 __attribute__((ext_vector_type(8)));     // 8 bf16 = 4 VGPRs
typedef float floatx4 __attribute__((ext_vector_type(4)));    // MFMA acc

__device__ __forceinline__ unsigned short f2bf(float f) {
    union { float f; unsigned int i; } v; v.f = f;
    unsigned int i = v.i;
    return (unsigned short)((i + 0x7fffu + ((i >> 16) & 1u)) >> 16);
}
// f32 pair -> packed bf16 (RTNE), lowers to v_cvt_pk_bf16_f32 on gfx950
__device__ __forceinline__ unsigned int cvt2(float lo, float hi) {
    __hip_bfloat162 h = __float22bfloat162_rn(float2{lo, hi});
    union { __hip_bfloat162 h; unsigned int u; } cv; cv.h = h;
    return cv.u;
}

// Bfr fragment-order index: element (n, k) -> short index.
// Wave reads 16B at block ((n>>4)*26 + (k>>5)), lane offset ((k>>3)&3)*16 + (n&15).
__device__ __forceinline__ size_t bfr_idx(int n, int k) {
    return ((((size_t)(n >> 4) * 26 + (k >> 5)) * 64
             + ((k >> 3) & 3) * 16 + (n & 15)) * 8) + (k & 7);
}

// ---------------------------------------------------------------------------
// K_prep: blocks 0..511 build Bfr row a (fragment-ordered); 512..543: query b;
// 544..575: zero energy for batch b (replaces hipMemsetAsync dispatch).
__global__ __launch_bounds__(256) void k_prep(
    const float* __restrict__ hidden,
    const float* __restrict__ Wh,
    const float* __restrict__ bh,
    const float* __restrict__ bec,
    const float* __restrict__ Wec,
    const float* __restrict__ Wac,
    const float* __restrict__ Waw,
    float* __restrict__ query,
    unsigned short* __restrict__ Bfr,
    float* __restrict__ energy)
{
    __shared__ float sbuf[512];
    const int blk = blockIdx.x, t = threadIdx.x;
    if (blk < 512) {
        const int a = blk;
        sbuf[t]       = Waw[(size_t)a * 512 + t];
        sbuf[t + 256] = Waw[(size_t)a * 512 + t + 256];
        __syncthreads();
        for (int cp = t; cp < Cn; cp += 256)
            Bfr[bfr_idx(a, cp)] = f2bf(Wec[(size_t)a * Cn + cp]);
        if (t < KKn) {
            float s = 0.f;
            #pragma unroll 8
            for (int k = 0; k < 512; ++k)
                s = fmaf(sbuf[k], Wac[k * KKn + t], s);
            Bfr[bfr_idx(a, Cn + t)] = f2bf(s);
        }
        for (int cp = CREAL + t; cp < CPAD; cp += 256)
            Bfr[bfr_idx(a, cp)] = 0;
    } else if (blk < 544) {
        const int b = blk - 512;
        sbuf[t] = (t < HIDn) ? hidden[b * HIDn + t] : 0.f;
        __syncthreads();
        for (int a = t; a < An; a += 256) {
            const float4* wp = (const float4*)(Wh + (size_t)a * HIDn);
            float s = bh[a] + bec[a];
            #pragma unroll 8
            for (int i = 0; i < HIDn / 4; ++i) {
                float4 w = wp[i];
                s = fmaf(sbuf[4 * i],     w.x, s);
                s = fmaf(sbuf[4 * i + 1], w.y, s);
                s = fmaf(sbuf[4 * i + 2], w.z, s);
                s = fmaf(sbuf[4 * i + 3], w.w, s);
            }
            query[b * An + a] = s;
        }
    } else {
        const int b = blk - 544;
        #pragma unroll
        for (int i = 0; i < 4; ++i)
            energy[b * HWn + i * 256 + t] = 0.f;
    }
}

// ---------------------------------------------------------------------------
// K_energy v8: 8-wave blocks, spill-free.
//  - Block = 512 thr / 8 waves; wave owns 64m x 32n (nf=2) -> acc 32 VGPR,
//    af 16, bf 8: ~80 live regs < 128 cap of __launch_bounds__(512,4)
//    (R3's (256,4) + 64-reg acc spilled: WRITE_SIZE 0.25->50MB).
//  - 2 blocks/CU = 16 waves/CU; grid 1024 = exactly 2 clean rounds.
//  - B fragments: direct global->reg dwordx4 from fragment-ordered Bfr (L2).
//  - A: shared staging; wave w stages rows ch*32+w*4..+3 (wave-uniform ->
//    X-vs-plane branch never diverges). Tail im2col via LDS LUT (no idiv,
//    no per-element triple branch; plane has a zero-pad region for rows>=805).
//  - One barrier per chunk (proven schedule), double-buffered As.
// Grid 1D 1024, XCD-pair swizzle (FETCH 91->50MB, kept from R2).
__global__ __launch_bounds__(512, 4) void k_energy(
    const float* __restrict__ X,
    const float* __restrict__ asum,
    const float* __restrict__ Wv,
    const float* __restrict__ query,
    const unsigned short* __restrict__ Bfr,
    float* __restrict__ energy)
{
    __shared__ __align__(16) unsigned short As[2][64 * 40];   // 10,240B, stride 40
    __shared__ float plane[878];          // 814 im2col + 64 zero pad
    __shared__ int   lut[148];            // row-684 -> plane offset (or pad)
    __shared__ float qs[NBLK];
    __shared__ float wvs[NBLK];
    __shared__ float red[8][64];

    const int t = threadIdx.x;
    const int d = blockIdx.x;
    const int nh  = (d >> 3) & 1;
    const int pid = (d >> 4) * 8 + (d & 7);
    const int hh = pid & 15, b = pid >> 4;
    const int w = t >> 6, lane = t & 63;
    const int q = lane >> 4, r = lane & 15;
    const int nbase = nh * NBLK;
    const int mA = lane;                   // staging: m index; wave w -> k rows w*4..w*4+3

    const float* Xb = X + (size_t)b * Cn * HWn + hh * Wn;
    const unsigned short* Bp = Bfr + (size_t)(nh * 16 + w * 2) * 26 * 512;

    // ---- prologue: plane(+zero pad) / lut / qs / wvs / chunk 0
    for (int i = t; i < 878; i += 512) {
        float v = 0.f;
        if (i < 814) {
            int di = i / 74, cc = i - di * 74;
            int h2 = hh + di - 5, w2 = cc - 5;
            if (h2 >= 0 && h2 < Hn && w2 >= 0 && w2 < Wn)
                v = asum[b * HWn + h2 * Wn + w2];
        }
        plane[i] = v;
    }
    if (t < 148) {
        int off = 814;                    // zero-pad region
        if (t < 121) { int di = t / 11; off = di * 74 + (t - di * 11); }
        lut[t] = off;
    }
    if (t < NBLK) {
        qs[t]  = query[b * An + nbase + t];
        wvs[t] = Wv[nbase + t];
    }
    // stage A chunk 0: wave w loads rows w*4..w*4+3 (pure X)
    {
        const float* xp = Xb + (size_t)(w * 4) * HWn + mA;
        float v0 = xp[0];
        float v1 = xp[(size_t)1 * HWn];
        float v2 = xp[(size_t)2 * HWn];
        float v3 = xp[(size_t)3 * HWn];
        *(uint2*)&As[0][mA * 40 + w * 4] = make_uint2(cvt2(v0, v1), cvt2(v2, v3));
    }
    __syncthreads();

    floatx4 acc[4][2];
    #pragma unroll
    for (int mf = 0; mf < 4; ++mf)
        #pragma unroll
        for (int nf = 0; nf < 2; ++nf)
            acc[mf][nf] = (floatx4){0.f, 0.f, 0.f, 0.f};

    for (int ch = 0; ch < NSTEP; ++ch) {
        const int cur = ch & 1;

        // (1) B fragments for this chunk: coalesced 1KB/wave-load from L2
        short8 bf[2];
        #pragma unroll
        for (int nf = 0; nf < 2; ++nf)
            bf[nf] = *(const short8*)(Bp + ((size_t)(nf * 26 + ch)) * 512 + lane * 8);

        // (2) A fragments of current chunk from LDS
        short8 af[4];
        #pragma unroll
        for (int mf = 0; mf < 4; ++mf)
            af[mf] = *(const short8*)&As[cur][(mf * 16 + r) * 40 + q * 8];

        // (3) stage next chunk (4 rows per wave, wave-uniform branch)
        if (ch < NSTEP - 1) {
            const int c0 = (ch + 1) * 32 + w * 4;
            float va[4];
            #pragma unroll
            for (int j = 0; j < 4; ++j) {
                const int row = c0 + j;
                if (row < Cn) va[j] = Xb[(size_t)row * HWn + mA];
                else          va[j] = plane[lut[row - Cn] + mA];
            }
            *(uint2*)&As[cur ^ 1][mA * 40 + w * 4] =
                make_uint2(cvt2(va[0], va[1]), cvt2(va[2], va[3]));
        }

        // (4) MFMA
        #pragma unroll
        for (int mf = 0; mf < 4; ++mf)
            #pragma unroll
            for (int nf = 0; nf < 2; ++nf)
                acc[mf][nf] = __builtin_amdgcn_mfma_f32_16x16x32_bf16(
                    af[mf], bf[nf], acc[mf][nf], 0, 0, 0);

        // (5) single barrier protects the A double-buffer
        __syncthreads();
    }

    // ---- epilogue: e[m] = sum_n Wv[n]*tanh(acc + query[n])
    float ep[16];
    #pragma unroll
    for (int i = 0; i < 16; ++i) ep[i] = 0.f;
    #pragma unroll
    for (int nf = 0; nf < 2; ++nf) {
        int nl = w * 32 + nf * 16 + r;
        float qv = qs[nl], wv = wvs[nl];
        #pragma unroll
        for (int mf = 0; mf < 4; ++mf)
            #pragma unroll
            for (int rg = 0; rg < 4; ++rg) {
                float x = acc[mf][nf][rg] + qv;
                float e2 = __expf(2.f * x);
                float th = 1.f - 2.f * __builtin_amdgcn_rcpf(e2 + 1.f);
                ep[mf * 4 + rg] += wv * th;
            }
    }
    // reduce over the 16 r-lanes (lane bits 0..3) via shfl_xor
    #pragma unroll
    for (int i = 0; i < 16; ++i) {
        #pragma unroll
        for (int msk = 1; msk <= 8; msk <<= 1)
            ep[i] += __shfl_xor(ep[i], msk, 64);
    }
    if (r == 0) {
        #pragma unroll
        for (int mf = 0; mf < 4; ++mf)
            #pragma unroll
            for (int rg = 0; rg < 4; ++rg)
                red[w][mf * 16 + q * 4 + rg] = ep[mf * 4 + rg];
    }
    __syncthreads();
    if (t < 64) {
        float s = 0.f;
        #pragma unroll
        for (int ww = 0; ww < 8; ++ww) s += red[ww][t];
        atomicAdd(&energy[b * HWn + hh * Wn + t], s);
    }
}

// ---------------------------------------------------------------------------
// K_softmax: one block per batch. alpha from energy once, written in-place
// over energy, plus alpha / alpha_sum_new outputs.
__global__ __launch_bounds__(256) void k_softmax(
    const float* __restrict__ mask,
    const float* __restrict__ asum,
    float* __restrict__ energy,     // in: energy, out: alpha
    float* __restrict__ out)
{
    __shared__ float rsm[8];
    const int b = blockIdx.x;
    const int t = threadIdx.x, lane = t & 63, wid = t >> 6;

    float e[4], ex[4];
    #pragma unroll
    for (int i = 0; i < 4; ++i) e[i] = energy[b * HWn + i * 256 + t];
    float m = fmaxf(fmaxf(e[0], e[1]), fmaxf(e[2], e[3]));
    for (int off = 32; off >= 1; off >>= 1) m = fmaxf(m, __shfl_down(m, off, 64));
    if (lane == 0) rsm[wid] = m;
    __syncthreads();
    if (t == 0)
        rsm[4] = fmaxf(fmaxf(rsm[0], rsm[1]), fmaxf(rsm[2], rsm[3]));
    __syncthreads();
    const float M = rsm[4];
    float s = 0.f;
    #pragma unroll
    for (int i = 0; i < 4; ++i) {
        ex[i] = expf(e[i] - M) * mask[b * HWn + i * 256 + t];
        s += ex[i];
    }
    for (int off = 32; off >= 1; off >>= 1) s += __shfl_down(s, off, 64);
    __syncthreads();
    if (lane == 0) rsm[wid] = s;
    __syncthreads();
    if (t == 0) rsm[5] = rsm[0] + rsm[1] + rsm[2] + rsm[3] + 1e-10f;
    __syncthreads();
    const float denom = rsm[5];
    #pragma unroll
    for (int i = 0; i < 4; ++i) {
        int p = i * 256 + t;
        float a = ex[i] / denom;
        energy[b * HWn + p] = a;
        out[OUT_ALPHA + b * HWn + p] = a;
        out[OUT_ASUM  + b * HWn + p] = a + asum[b * HWn + p];
    }
}

// ---------------------------------------------------------------------------
// K_ctx: pure context GEMV. Grid (171, 32); block caches alpha in LDS,
// wave wid handles channel bx*4+wid. Streams X once.
__global__ __launch_bounds__(256) void k_ctx(
    const float* __restrict__ X,
    const float* __restrict__ alpha,
    float* __restrict__ out)
{
    __shared__ float al[1024];
    const int bx = blockIdx.x, b = blockIdx.y;
    const int t = threadIdx.x, lane = t & 63, wid = t >> 6;

    #pragma unroll
    for (int i = 0; i < 4; ++i) al[i * 256 + t] = alpha[b * HWn + i * 256 + t];
    __syncthreads();

    const int c = bx * 4 + wid;
    const float* xp = X + ((size_t)(b * Cn + c)) * HWn;
    float s2 = 0.f;
    #pragma unroll
    for (int i = 0; i < 4; ++i) {
        int off = i * 256 + lane * 4;
        float4 x = *(const float4*)(xp + off);
        float4 a = *(const float4*)(al + off);
        s2 = fmaf(a.x, x.x, s2);
        s2 = fmaf(a.y, x.y, s2);
        s2 = fmaf(a.z, x.z, s2);
        s2 = fmaf(a.w, x.w, s2);
    }
    for (int off = 32; off >= 1; off >>= 1) s2 += __shfl_down(s2, off, 64);
    if (lane == 0) out[b * Cn + c] = s2;
}

// ---------------------------------------------------------------------------
extern "C" void kernel_launch(void* const* d_in, const int* in_sizes, int n_in,
                              void* d_out, int out_size, void* d_ws, size_t ws_size,
                              hipStream_t stream)
{
    const float* X      = (const float*)d_in[0];
    const float* hidden = (const float*)d_in[1];
    const float* asum   = (const float*)d_in[2];
    const float* mask   = (const float*)d_in[3];
    const float* Wh     = (const float*)d_in[4];
    const float* bh     = (const float*)d_in[5];
    const float* Wec    = (const float*)d_in[6];
    const float* bec    = (const float*)d_in[7];
    const float* Wac    = (const float*)d_in[8];
    const float* Waw    = (const float*)d_in[9];
    const float* Wv     = (const float*)d_in[10];
    (void)in_sizes; (void)n_in; (void)out_size; (void)ws_size;

    float* out = (float*)d_out;
    float* ws = (float*)d_ws;
    float* query  = ws;                                    // 16384 floats
    float* energy = ws + 16384;                            // 32768 (energy -> alpha)
    unsigned short* Bfr = (unsigned short*)(ws + 16384 + 32768); // 512*832 bf16

    k_prep    <<<dim3(576),      dim3(256), 0, stream>>>(hidden, Wh, bh, bec,
                                                         Wec, Wac, Waw, query, Bfr, energy);
    k_energy  <<<dim3(1024),     dim3(512), 0, stream>>>(X, asum, Wv, query, Bfr, energy);
    k_softmax <<<dim3(32),       dim3(256), 0, stream>>>(mask, asum, energy, out);
    k_ctx     <<<dim3(171, 32),  dim3(256), 0, stream>>>(X, energy, out);
}